// Round 17
// baseline (24.628 us; speedup 1.0000x reference)
//
#include <hip/hip_runtime.h>

#define BATCH  2048
#define NIN    128
#define NOUT   128
#define T      128
#define XLO    (-6.0f)
#define XRANGE 12.0f
#define NCHUNK 8
#define ILEN   16              // i's per chunk = waves per block
#define JTILE  4               // j's per block (2 pairs)
#define L2E    1.44269504088896340736f

typedef float v2f __attribute__((ext_vector_type(2)));
typedef unsigned int u32;

__device__ __forceinline__ v2f splat(float s) { v2f v; v.x = s; v.y = s; return v; }

// v2f silu with paired rcp: 2 exp + 1 rcp
__device__ __forceinline__ v2f silu2(v2f x) {
    float e0 = __builtin_amdgcn_exp2f(x.x * -L2E);
    float e1 = __builtin_amdgcn_exp2f(x.y * -L2E);
    float d0 = 1.0f + e0, d1 = 1.0f + e1;
    float rp = __builtin_amdgcn_rcpf(d0 * d1);
    v2f r; r.x = x.x * rp * d1; r.y = x.y * rp * d0;
    return r;
}

__device__ __forceinline__ void silu_pair(float& u, float& v) {
    float eu = __builtin_amdgcn_exp2f(u * -L2E);
    float ev = __builtin_amdgcn_exp2f(v * -L2E);
    float du = 1.0f + eu, dv = 1.0f + ev;
    float rp = __builtin_amdgcn_rcpf(du * dv);
    float su = u * rp * dv;
    float sv = v * rp * du;
    u = su; v = sv;
}

__device__ __forceinline__ float silu_f(float x) {
    float e = __builtin_amdgcn_exp2f(x * -L2E);
    return x * __builtin_amdgcn_rcpf(1.0f + e);
}

__device__ __forceinline__ u32 bf16rn(float v) {   // RN-even bf16 bits
    u32 b = __float_as_uint(v);
    return (b + 0x7fffu + ((b >> 16) & 1u)) >> 16;
}

// 1-5-5-1 subnet on a knot pair: returns s*y + r*x
__device__ __forceinline__ v2f net_v2(
    const float* __restrict__ w0, const float* __restrict__ b0,
    const float* __restrict__ w1, const float* __restrict__ b1,
    const float* __restrict__ w2, const float* __restrict__ b2a,
    const float* __restrict__ s,  const float* __restrict__ r,
    int nw, v2f xv)
{
    const int n5 = nw * 5, n25 = nw * 25;
    v2f a[5];
    #pragma unroll
    for (int k = 0; k < 5; ++k)
        a[k] = silu2(w0[n5 + k] * xv + splat(b0[n5 + k]));
    v2f h2[5];
    #pragma unroll
    for (int k = 0; k < 5; ++k) {
        v2f u = splat(b1[n5 + k]);
        #pragma unroll
        for (int l = 0; l < 5; ++l)
            u = w1[n25 + k * 5 + l] * a[l] + u;
        h2[k] = silu2(u);
    }
    v2f y = splat(b2a[nw]);
    #pragma unroll
    for (int l = 0; l < 5; ++l)
        y = w2[n5 + l] * h2[l] + y;
    return y * s[nw] + xv * r[nw];
}

// ---- fused: build 64 tables in LDS (1 ii per wave), then eval 4 j's, all b ----
// tab layout [jp][ii][knot] of uint2 (j-pair packed); lerp via v_dot2_f32_bf16
__global__ __launch_bounds__(1024) void kfused(
    const float* __restrict__ x,
    const float* __restrict__ w00, const float* __restrict__ b00,
    const float* __restrict__ w01, const float* __restrict__ b01,
    const float* __restrict__ w02, const float* __restrict__ b02,
    const float* __restrict__ s0,  const float* __restrict__ r0,
    float* __restrict__ hTs,
    float* __restrict__ out)
{
    __shared__ uint2 tab[2 * ILEN * T];     // [jp][ii][knot] = 32 KB
    const int tid  = threadIdx.x;
    const int c    = blockIdx.x;            // i-chunk 0..7
    const int jg   = blockIdx.y;            // j-group 0..31
    const int j0   = jg * JTILE;
    const int i0   = c * ILEN;
    const int w    = tid >> 6;              // wave id 0..15 = ii (wave-uniform)
    const int lane = tid & 63;

    // zero out[] for klayer1's atomics (jg==0, c<2 blocks cover all 2048)
    if (jg == 0 && c < 2) out[c * 1024 + tid] = 0.0f;

    // ---------- phase 1: build; wave w builds ii=w for j-pairs jp=0,1 ----------
    const float h  = XRANGE / (float)(T - 1);
    const int   k2 = lane * 2;
    v2f xv;
    xv.x = XLO + (float)k2 * h;
    xv.y = XLO + (float)(k2 + 1) * h;

    #pragma unroll
    for (int jp = 0; jp < 2; ++jp) {
        const int nwb = (i0 + w) * NOUT + (j0 + 2 * jp);

        v2f ga = net_v2(w00, b00, w01, b01, w02, b02, s0, r0,
                        __builtin_amdgcn_readfirstlane(nwb), xv);
        v2f gb = net_v2(w00, b00, w01, b01, w02, b02, s0, r0,
                        __builtin_amdgcn_readfirstlane(nwb + 1), xv);

        float yna = __shfl_down(ga.x, 1, 64);   // y at knot k2+2 (j even)
        float ynb = __shfl_down(gb.x, 1, 64);   // y at knot k2+2 (j odd)

        uint4 q;
        q.x = (bf16rn(ga.x) << 16) | bf16rn(ga.y - ga.x);   // knot k2,   j even
        q.y = (bf16rn(gb.x) << 16) | bf16rn(gb.y - gb.x);   // knot k2,   j odd
        q.z = (bf16rn(ga.y) << 16) | bf16rn(yna - ga.y);    // knot k2+1, j even
        q.w = (bf16rn(gb.y) << 16) | bf16rn(ynb - gb.y);    // knot k2+1, j odd

        *(uint4*)&tab[(jp * ILEN + w) * T + k2] = q;        // 16B-aligned b128
    }
    __syncthreads();

    // ---------- phase 2: eval, 2 passes x 1024 threads over batch ----------
    const float invh = (float)(T - 1) / XRANGE;
    const float tofs = -XLO * invh;
    const float onef = 1.0f;

    #pragma unroll
    for (int p = 0; p < 2; ++p) {
        const int b = p * 1024 + tid;
        const float4* xp = (const float4*)(x + (size_t)b * NIN + i0);
        float4 xq[4];
        xq[0] = xp[0]; xq[1] = xp[1]; xq[2] = xp[2]; xq[3] = xp[3];

        float acc0 = 0.0f, acc1 = 0.0f, acc2 = 0.0f, acc3 = 0.0f;

        #pragma unroll
        for (int q = 0; q < 4; ++q) {
            #pragma unroll
            for (int e = 0; e < 4; ++e) {
                const int ii = q * 4 + e;
                const float xval = (e == 0) ? xq[q].x : (e == 1) ? xq[q].y
                                 : (e == 2) ? xq[q].z : xq[q].w;
                float t = fmaf(xval, invh, tofs);
                t = fminf(fmaxf(t, 0.0f), (float)(T - 2));  // v_med3 clamp
                const int   idx = (int)t;
                const float f   = __builtin_amdgcn_fractf(t);

                // S0 = (lo=bf16(f), hi=bf16(1.0)) in one packed convert
                u32 fo;
                asm("v_cvt_pk_bf16_f32 %0, %1, %2" : "=v"(fo) : "v"(f), "v"(onef));

                // 2 b64 gathers (one vaddr + 16KB imm offset)
                const uint2 qa = tab[(0 * ILEN + ii) * T + idx];
                const uint2 qb = tab[(1 * ILEN + ii) * T + idx];

                // acc += f*dy + 1*y  (table word: hi=y, lo=dy)
                asm("v_dot2_f32_bf16 %0, %1, %2, %0" : "+v"(acc0) : "v"(fo), "v"(qa.x));
                asm("v_dot2_f32_bf16 %0, %1, %2, %0" : "+v"(acc1) : "v"(fo), "v"(qa.y));
                asm("v_dot2_f32_bf16 %0, %1, %2, %0" : "+v"(acc2) : "v"(fo), "v"(qb.x));
                asm("v_dot2_f32_bf16 %0, %1, %2, %0" : "+v"(acc3) : "v"(fo), "v"(qb.y));
            }
        }

        hTs[((size_t)c * NOUT + j0 + 0) * BATCH + b] = acc0;
        hTs[((size_t)c * NOUT + j0 + 1) * BATCH + b] = acc1;
        hTs[((size_t)c * NOUT + j0 + 2) * BATCH + b] = acc2;
        hTs[((size_t)c * NOUT + j0 + 3) * BATCH + b] = acc3;
    }
}

// -------- layer 1 (second KAN layer): analytic, sums partial slices --------
#define IPB 2
__global__ __launch_bounds__(64) void klayer1(
    const float* __restrict__ hTs,
    const float* __restrict__ w0, const float* __restrict__ bb0,
    const float* __restrict__ w1, const float* __restrict__ bb1,
    const float* __restrict__ w2, const float* __restrict__ bb2,
    const float* __restrict__ s,  const float* __restrict__ r,
    float* __restrict__ out)
{
    const int b  = blockIdx.x * 64 + threadIdx.x;
    const int i0 = blockIdx.y * IPB;

    float acc = 0.0f;

    #pragma unroll
    for (int ii = 0; ii < IPB; ++ii) {
        const int i  = i0 + ii;
        const int i5 = i * 5, i25 = i * 25;

        float xv = 0.0f;
        #pragma unroll
        for (int cc = 0; cc < NCHUNK; ++cc)
            xv += hTs[((size_t)cc * NOUT + i) * BATCH + b];

        float a[5];
        #pragma unroll
        for (int k = 0; k < 5; ++k)
            a[k] = fmaf(w0[i5 + k], xv, bb0[i5 + k]);
        silu_pair(a[0], a[1]);
        silu_pair(a[2], a[3]);
        a[4] = silu_f(a[4]);

        float h2[5];
        #pragma unroll
        for (int k = 0; k < 5; ++k) {
            float u = bb1[i5 + k];
            #pragma unroll
            for (int l = 0; l < 5; ++l)
                u = fmaf(w1[i25 + k * 5 + l], a[l], u);
            h2[k] = u;
        }
        silu_pair(h2[0], h2[1]);
        silu_pair(h2[2], h2[3]);
        h2[4] = silu_f(h2[4]);

        float y = bb2[i];
        #pragma unroll
        for (int l = 0; l < 5; ++l)
            y = fmaf(w2[i5 + l], h2[l], y);

        acc = fmaf(y, s[i], fmaf(xv, r[i], acc));
    }

    atomicAdd(&out[b], acc);
}

extern "C" void kernel_launch(void* const* d_in, const int* in_sizes, int n_in,
                              void* d_out, int out_size, void* d_ws, size_t ws_size,
                              hipStream_t stream) {
    const float* x    = (const float*)d_in[0];
    const float* w0_0 = (const float*)d_in[1];
    const float* b0_0 = (const float*)d_in[2];
    const float* w0_1 = (const float*)d_in[3];
    const float* b0_1 = (const float*)d_in[4];
    const float* w0_2 = (const float*)d_in[5];
    const float* b0_2 = (const float*)d_in[6];
    const float* s0   = (const float*)d_in[7];
    const float* r0   = (const float*)d_in[8];
    const float* w1_0 = (const float*)d_in[9];
    const float* b1_0 = (const float*)d_in[10];
    const float* w1_1 = (const float*)d_in[11];
    const float* b1_1 = (const float*)d_in[12];
    const float* w1_2 = (const float*)d_in[13];
    const float* b1_2 = (const float*)d_in[14];
    const float* s1   = (const float*)d_in[15];
    const float* r1   = (const float*)d_in[16];

    float* out = (float*)d_out;
    float* hTs = (float*)d_ws;            // [NCHUNK][NOUT][BATCH] = 8 MB

    kfused<<<dim3(NCHUNK, NOUT / JTILE), 1024, 0, stream>>>(
        x, w0_0, b0_0, w0_1, b0_1, w0_2, b0_2, s0, r0, hTs, out);

    klayer1<<<dim3(BATCH / 64, NIN / IPB), 64, 0, stream>>>(
        hTs, w1_0, b1_0, w1_1, b1_1, w1_2, b1_2, s1, r1, out);
}